// Round 2
// baseline (1478.350 us; speedup 1.0000x reference)
//
#include <hip/hip_runtime.h>

#define N_USERS   200000
#define N_ITEMS   100000
#define DIM       64
#define N_NODES   300000
#define N_EDGES   1200000
#define BIN_SHIFT 8
#define NBINS     1172            // ceil(300000/256)
#define CHUNK     4096
#define NCHUNKS   293             // ceil(1200000/4096)

// ---- bf16 helpers (manual RNE; no NaN inputs here) ------------------------
__device__ __forceinline__ unsigned short f2b(float f) {
    unsigned u = __float_as_uint(f);
    u += 0x7FFFu + ((u >> 16) & 1u);
    return (unsigned short)(u >> 16);
}
__device__ __forceinline__ float blo(unsigned w) { return __uint_as_float(w << 16); }
__device__ __forceinline__ float bhi(unsigned w) { return __uint_as_float(w & 0xFFFF0000u); }
__device__ __forceinline__ unsigned packbf(float lo, float hi) {
    return (unsigned)f2b(lo) | ((unsigned)f2b(hi) << 16);
}

// ---------------------------------------------------------------------------
// Phase A1: per-chunk histogram over bins. int4 loads, 4 outstanding before use.
__global__ __launch_bounds__(256) void histA_kernel(const int* __restrict__ row,
                                                    int* __restrict__ histG,
                                                    int* __restrict__ binTot) {
    __shared__ int h[NBINS];
    for (int i = threadIdx.x; i < NBINS; i += 256) h[i] = 0;
    __syncthreads();
    const int4* row4 = (const int4*)row;
    int base4 = blockIdx.x * (CHUNK / 4);                 // N_EDGES % 4 == 0
    int end4  = min(base4 + CHUNK / 4, N_EDGES / 4);
    int i0 = base4 + threadIdx.x;
    int i1 = i0 + 256, i2 = i0 + 512, i3 = i0 + 768;
    int4 r0, r1, r2, r3;
    bool v0 = i0 < end4, v1 = i1 < end4, v2 = i2 < end4, v3 = i3 < end4;
    if (v0) r0 = row4[i0];
    if (v1) r1 = row4[i1];
    if (v2) r2 = row4[i2];
    if (v3) r3 = row4[i3];
    if (v0) { atomicAdd(&h[r0.x >> BIN_SHIFT], 1); atomicAdd(&h[r0.y >> BIN_SHIFT], 1);
              atomicAdd(&h[r0.z >> BIN_SHIFT], 1); atomicAdd(&h[r0.w >> BIN_SHIFT], 1); }
    if (v1) { atomicAdd(&h[r1.x >> BIN_SHIFT], 1); atomicAdd(&h[r1.y >> BIN_SHIFT], 1);
              atomicAdd(&h[r1.z >> BIN_SHIFT], 1); atomicAdd(&h[r1.w >> BIN_SHIFT], 1); }
    if (v2) { atomicAdd(&h[r2.x >> BIN_SHIFT], 1); atomicAdd(&h[r2.y >> BIN_SHIFT], 1);
              atomicAdd(&h[r2.z >> BIN_SHIFT], 1); atomicAdd(&h[r2.w >> BIN_SHIFT], 1); }
    if (v3) { atomicAdd(&h[r3.x >> BIN_SHIFT], 1); atomicAdd(&h[r3.y >> BIN_SHIFT], 1);
              atomicAdd(&h[r3.z >> BIN_SHIFT], 1); atomicAdd(&h[r3.w >> BIN_SHIFT], 1); }
    __syncthreads();
    for (int i = threadIdx.x; i < NBINS; i += 256) {
        int v = h[i];
        histG[blockIdx.x * NBINS + i] = v;
        if (v) atomicAdd(&binTot[i], v);
    }
}

// histG[chunk][bin] -> global start offsets: one 64-lane wave per bin.
// Bin prefix (exclusive scan of binTot) computed in-block by direct reduction
// over the L2-resident binTot array; then shfl-based scan over the 293 chunks.
__global__ __launch_bounds__(64) void rewrite_kernel(int* __restrict__ histG,
                                                     const int* __restrict__ binTot,
                                                     int* __restrict__ binStart) {
    int b    = blockIdx.x;
    int lane = threadIdx.x;
    int pre = 0;
    for (int i = lane; i < b; i += 64) pre += binTot[i];
#pragma unroll
    for (int off = 1; off < 64; off <<= 1) pre += __shfl_xor(pre, off, 64);
    if (lane == 0) binStart[b] = pre;
    if (b == 0 && lane == 0) binStart[NBINS] = N_EDGES;
    int carry = pre;
    for (int base = 0; base < NCHUNKS; base += 64) {
        int idx = base + lane;
        int v = (idx < NCHUNKS) ? histG[idx * NBINS + b] : 0;
        int incl = v;
        for (int off = 1; off < 64; off <<= 1) {
            int t = __shfl_up(incl, off, 64);
            if (lane >= off) incl += t;
        }
        if (idx < NCHUNKS) histG[idx * NBINS + b] = carry + incl - v;
        carry += __shfl(incl, 63, 64);
    }
}

// Phase A2: place packed (col<<8 | row&255) into bin-major tmp.
__global__ __launch_bounds__(256) void placeA_kernel(const int* __restrict__ row,
                                                     const int* __restrict__ col,
                                                     const int* __restrict__ histG,
                                                     int* __restrict__ tmp) {
    __shared__ int ofs[NBINS];
    for (int i = threadIdx.x; i < NBINS; i += 256)
        ofs[i] = histG[blockIdx.x * NBINS + i];
    __syncthreads();
    const int4* row4 = (const int4*)row;
    const int4* col4 = (const int4*)col;
    int base4 = blockIdx.x * (CHUNK / 4);
    int end4  = min(base4 + CHUNK / 4, N_EDGES / 4);
    int i0 = base4 + threadIdx.x;
    int i1 = i0 + 256, i2 = i0 + 512, i3 = i0 + 768;
    int4 r0, r1, r2, r3, c0, c1, c2, c3;
    bool v0 = i0 < end4, v1 = i1 < end4, v2 = i2 < end4, v3 = i3 < end4;
    if (v0) { r0 = row4[i0]; c0 = col4[i0]; }
    if (v1) { r1 = row4[i1]; c1 = col4[i1]; }
    if (v2) { r2 = row4[i2]; c2 = col4[i2]; }
    if (v3) { r3 = row4[i3]; c3 = col4[i3]; }
    auto put = [&](int r, int c) {
        int pos = atomicAdd(&ofs[r >> BIN_SHIFT], 1);
        tmp[pos] = (c << BIN_SHIFT) | (r & 255);
    };
    if (v0) { put(r0.x, c0.x); put(r0.y, c0.y); put(r0.z, c0.z); put(r0.w, c0.w); }
    if (v1) { put(r1.x, c1.x); put(r1.y, c1.y); put(r1.z, c1.z); put(r1.w, c1.w); }
    if (v2) { put(r2.x, c2.x); put(r2.y, c2.y); put(r2.z, c2.z); put(r2.w, c2.w); }
    if (v3) { put(r3.x, c3.x); put(r3.y, c3.y); put(r3.z, c3.z); put(r3.w, c3.w); }
}

// Phase B: per bin -- degree count only (no sort needed anymore), dis/invd,
// and fused conv g0 = x*dis (bf16) for the bin's 256 nodes.
__global__ __launch_bounds__(256) void prep_kernel(const int* __restrict__ tmp,
                                                   const int* __restrict__ binStart,
                                                   float* __restrict__ dis,
                                                   float* __restrict__ invd,
                                                   const float* __restrict__ ue,
                                                   const float* __restrict__ ie,
                                                   unsigned short* __restrict__ g0) {
    __shared__ int hist[256];
    int b = blockIdx.x;
    hist[threadIdx.x] = 0;
    __syncthreads();
    int jb = binStart[b], je = binStart[b + 1];
    for (int i = jb + threadIdx.x; i < je; i += 256)
        atomicAdd(&hist[tmp[i] & 255], 1);
    __syncthreads();
    int node = (b << BIN_SHIFT) + threadIdx.x;
    if (node < N_NODES) {
        int dg = hist[threadIdx.x];
        float fd = (float)dg;
        dis[node]  = dg ? rsqrtf(fd) : 0.0f;
        invd[node] = dg ? sqrtf(fd)  : 0.0f;
    }
    int q = threadIdx.x & 7;
    for (int pass = 0; pass < 8; ++pass) {
        int nl = (pass << 5) + (threadIdx.x >> 3);
        int nd = (b << BIN_SHIFT) + nl;
        if (nd >= N_NODES) break;
        int dg = hist[nl];
        float w = dg ? rsqrtf((float)dg) : 0.0f;
        const float* src = (nd < N_USERS) ? (ue + nd * DIM)
                                          : (ie + (nd - N_USERS) * DIM);
        float4 x0 = ((const float4*)src)[2 * q];
        float4 x1 = ((const float4*)src)[2 * q + 1];
        uint4 o;
        o.x = packbf(w * x0.x, w * x0.y);
        o.y = packbf(w * x0.z, w * x0.w);
        o.z = packbf(w * x1.x, w * x1.y);
        o.w = packbf(w * x1.z, w * x1.w);
        ((uint4*)(g0 + nd * DIM))[q] = o;
    }
}

// ---------------------------------------------------------------------------
// Edge-centric pull with LDS fp32 accumulation. One 512-thread block per bin
// (256 nodes); edges for the bin are contiguous in bin-major tmp and carry
// (col<<8 | row&255). No per-node dependent chain: the block streams its
// ~1024 edges with 4 gathers in flight per lane at all times; ds_add_f32
// accumulates into a 64 KB XOR-swizzled LDS tile. Epilogue scales & writes
// coalesced.  g_{l+1}[r] = dis_r^2 * sum g_l[c].
// FINAL: out = 0.25*(x + (g1+g2)*sqrt(deg) + dis*sum g2[c])
template <bool FINAL>
__global__ __launch_bounds__(512) void pull_kernel(
        const unsigned short* __restrict__ g_in,
        const int* __restrict__ tmp, const int* __restrict__ binStart,
        const float* __restrict__ dis, const float* __restrict__ invd,
        const float* __restrict__ ue, const float* __restrict__ ie,
        const unsigned short* __restrict__ gA,
        const unsigned short* __restrict__ gB,
        unsigned short* __restrict__ g_out,
        float* __restrict__ out) {
    __shared__ float acc[256 * 64];               // 64 KB, XOR-swizzled
    for (int i = threadIdx.x; i < 256 * 64; i += 512) acc[i] = 0.0f;
    __syncthreads();

    int b  = blockIdx.x;
    int jb = binStart[b], je = binStart[b + 1];
    int slot = threadIdx.x >> 3;                  // 0..63
    int q    = threadIdx.x & 7;
    int q8   = q << 3;
    const uint4* gin4 = (const uint4*)g_in;       // row = 8 uint4
    const unsigned* cr = (const unsigned*)tmp;

    auto lds_acc = [&](unsigned e, uint4 u) {
        int r  = (int)(e & 255u);
        int ab = r << 6;
        int sw = r & 31;
        atomicAdd(&acc[ab + ((q8 + 0) ^ sw)], blo(u.x));
        atomicAdd(&acc[ab + ((q8 + 1) ^ sw)], bhi(u.x));
        atomicAdd(&acc[ab + ((q8 + 2) ^ sw)], blo(u.y));
        atomicAdd(&acc[ab + ((q8 + 3) ^ sw)], bhi(u.y));
        atomicAdd(&acc[ab + ((q8 + 4) ^ sw)], blo(u.z));
        atomicAdd(&acc[ab + ((q8 + 5) ^ sw)], bhi(u.z));
        atomicAdd(&acc[ab + ((q8 + 6) ^ sw)], blo(u.w));
        atomicAdd(&acc[ab + ((q8 + 7) ^ sw)], bhi(u.w));
    };

    int base = jb;
    for (; base + 256 <= je; base += 256) {       // 64 slots x 4-unroll
        unsigned u0 = cr[base + slot];
        unsigned u1 = cr[base + 64 + slot];
        unsigned u2 = cr[base + 128 + slot];
        unsigned u3 = cr[base + 192 + slot];
        uint4 a0 = gin4[(u0 >> 8) * 8 + q];
        uint4 a1 = gin4[(u1 >> 8) * 8 + q];
        uint4 a2 = gin4[(u2 >> 8) * 8 + q];
        uint4 a3 = gin4[(u3 >> 8) * 8 + q];
        lds_acc(u0, a0); lds_acc(u1, a1); lds_acc(u2, a2); lds_acc(u3, a3);
    }
    for (int e = base + slot; e < je; e += 64) {  // tail (< 256 edges)
        unsigned u = cr[e];
        uint4 a = gin4[(u >> 8) * 8 + q];
        lds_acc(u, a);
    }
    __syncthreads();

    // epilogue: 256 rows x 8 q-chunks = 2048 tasks / 512 threads = 4 each
    for (int k = 0; k < 4; ++k) {
        int r    = slot + (k << 6);
        int node = (b << 8) + r;
        if (node >= N_NODES) break;
        int ab = r << 6;
        int sw = r & 31;
        float v0 = acc[ab + ((q8 + 0) ^ sw)];
        float v1 = acc[ab + ((q8 + 1) ^ sw)];
        float v2 = acc[ab + ((q8 + 2) ^ sw)];
        float v3 = acc[ab + ((q8 + 3) ^ sw)];
        float v4 = acc[ab + ((q8 + 4) ^ sw)];
        float v5 = acc[ab + ((q8 + 5) ^ sw)];
        float v6 = acc[ab + ((q8 + 6) ^ sw)];
        float v7 = acc[ab + ((q8 + 7) ^ sw)];
        float dr = dis[node];
        if (!FINAL) {
            float s = dr * dr;
            uint4 o;
            o.x = packbf(s * v0, s * v1);
            o.y = packbf(s * v2, s * v3);
            o.z = packbf(s * v4, s * v5);
            o.w = packbf(s * v6, s * v7);
            ((uint4*)(g_out + node * DIM))[q] = o;
        } else {
            float iv = invd[node];
            const float* xs = (node < N_USERS) ? (ue + node * DIM)
                                               : (ie + (node - N_USERS) * DIM);
            float4 x0 = ((const float4*)xs)[2 * q];
            float4 x1 = ((const float4*)xs)[2 * q + 1];
            uint4 a = ((const uint4*)gA)[node * 8 + q];
            uint4 bb = ((const uint4*)gB)[node * 8 + q];
            float4 o0, o1;
            o0.x = 0.25f * (x0.x + (blo(a.x) + blo(bb.x)) * iv + dr * v0);
            o0.y = 0.25f * (x0.y + (bhi(a.x) + bhi(bb.x)) * iv + dr * v1);
            o0.z = 0.25f * (x0.z + (blo(a.y) + blo(bb.y)) * iv + dr * v2);
            o0.w = 0.25f * (x0.w + (bhi(a.y) + bhi(bb.y)) * iv + dr * v3);
            o1.x = 0.25f * (x1.x + (blo(a.z) + blo(bb.z)) * iv + dr * v4);
            o1.y = 0.25f * (x1.y + (bhi(a.z) + bhi(bb.z)) * iv + dr * v5);
            o1.z = 0.25f * (x1.z + (blo(a.w) + blo(bb.w)) * iv + dr * v6);
            o1.w = 0.25f * (x1.w + (bhi(a.w) + bhi(bb.w)) * iv + dr * v7);
            ((float4*)out)[node * 16 + 2 * q]     = o0;
            ((float4*)out)[node * 16 + 2 * q + 1] = o1;
        }
    }
}

extern "C" void kernel_launch(void* const* d_in, const int* in_sizes, int n_in,
                              void* d_out, int out_size, void* d_ws, size_t ws_size,
                              hipStream_t stream) {
    const float* ue  = (const float*)d_in[0];
    const float* ie  = (const float*)d_in[1];
    const int*   ei  = (const int*)d_in[2];
    const int*   row = ei;
    const int*   col = ei + N_EDGES;
    float*       out = (float*)d_out;

    // workspace layout
    size_t gElems = (size_t)N_NODES * DIM;                 // 19.2 M
    unsigned short* g0 = (unsigned short*)d_ws;            // 38.4 MB
    unsigned short* g1 = g0 + gElems;                      // 38.4 MB
    unsigned short* g2 = g1 + gElems;                      // 38.4 MB
    int*   tmp      = (int*)(g2 + gElems);                 // 4.8 MB (packed edges)
    float* dis      = (float*)(tmp + N_EDGES);
    float* invd     = dis + N_NODES;
    int*   histG    = (int*)(invd + N_NODES);              // 293*1172*4 = 1.37 MB
    int*   binTot   = histG + NCHUNKS * NBINS;
    int*   binStart = binTot + NBINS;

    const int B = 256;

    // ---- CSR-lite build: bin-major packed edges + degrees, no sort ----
    hipMemsetAsync(binTot, 0, (size_t)NBINS * sizeof(int), stream);
    histA_kernel   <<<NCHUNKS, B, 0, stream>>>(row, histG, binTot);
    rewrite_kernel <<<NBINS, 64, 0, stream>>>(histG, binTot, binStart);
    placeA_kernel  <<<NCHUNKS, B, 0, stream>>>(row, col, histG, tmp);
    prep_kernel    <<<NBINS, B, 0, stream>>>(tmp, binStart, dis, invd, ue, ie, g0);

    // ---- 3 bf16 edge-centric pull layers; acc+scale fused into the last ----
    pull_kernel<false><<<NBINS, 512, 0, stream>>>(g0, tmp, binStart, dis, invd,
                                                  nullptr, nullptr, nullptr, nullptr,
                                                  g1, nullptr);
    pull_kernel<false><<<NBINS, 512, 0, stream>>>(g1, tmp, binStart, dis, invd,
                                                  nullptr, nullptr, nullptr, nullptr,
                                                  g2, nullptr);
    pull_kernel<true ><<<NBINS, 512, 0, stream>>>(g2, tmp, binStart, dis, invd,
                                                  ue, ie, g1, g2, nullptr, out);
}

// Round 3
// 309.917 us; speedup vs baseline: 4.7701x; 4.7701x over previous
//
#include <hip/hip_runtime.h>

#define N_USERS   200000
#define N_ITEMS   100000
#define DIM       64
#define N_NODES   300000
#define N_EDGES   1200000
#define BIN_SHIFT 8
#define NBINS     1172            // ceil(300000/256)
#define CHUNK     4096
#define NCHUNKS   293             // ceil(1200000/4096)
#define BIN_CAP   2048            // mean edges/bin = 1024 -> huge margin

// ---- bf16 helpers (manual RNE; no NaN inputs here) ------------------------
__device__ __forceinline__ unsigned short f2b(float f) {
    unsigned u = __float_as_uint(f);
    u += 0x7FFFu + ((u >> 16) & 1u);
    return (unsigned short)(u >> 16);
}
__device__ __forceinline__ float blo(unsigned w) { return __uint_as_float(w << 16); }
__device__ __forceinline__ float bhi(unsigned w) { return __uint_as_float(w & 0xFFFF0000u); }
__device__ __forceinline__ unsigned packbf(float lo, float hi) {
    return (unsigned)f2b(lo) | ((unsigned)f2b(hi) << 16);
}

// ---------------------------------------------------------------------------
// Phase A1: per-chunk histogram over bins. int4 loads, 4 outstanding before use.
__global__ __launch_bounds__(256) void histA_kernel(const int* __restrict__ row,
                                                    int* __restrict__ histG,
                                                    int* __restrict__ binTot) {
    __shared__ int h[NBINS];
    for (int i = threadIdx.x; i < NBINS; i += 256) h[i] = 0;
    __syncthreads();
    const int4* row4 = (const int4*)row;
    int base4 = blockIdx.x * (CHUNK / 4);                 // N_EDGES % 4 == 0
    int end4  = min(base4 + CHUNK / 4, N_EDGES / 4);
    int i0 = base4 + threadIdx.x;
    int i1 = i0 + 256, i2 = i0 + 512, i3 = i0 + 768;
    int4 r0, r1, r2, r3;
    bool v0 = i0 < end4, v1 = i1 < end4, v2 = i2 < end4, v3 = i3 < end4;
    if (v0) r0 = row4[i0];
    if (v1) r1 = row4[i1];
    if (v2) r2 = row4[i2];
    if (v3) r3 = row4[i3];
    if (v0) { atomicAdd(&h[r0.x >> BIN_SHIFT], 1); atomicAdd(&h[r0.y >> BIN_SHIFT], 1);
              atomicAdd(&h[r0.z >> BIN_SHIFT], 1); atomicAdd(&h[r0.w >> BIN_SHIFT], 1); }
    if (v1) { atomicAdd(&h[r1.x >> BIN_SHIFT], 1); atomicAdd(&h[r1.y >> BIN_SHIFT], 1);
              atomicAdd(&h[r1.z >> BIN_SHIFT], 1); atomicAdd(&h[r1.w >> BIN_SHIFT], 1); }
    if (v2) { atomicAdd(&h[r2.x >> BIN_SHIFT], 1); atomicAdd(&h[r2.y >> BIN_SHIFT], 1);
              atomicAdd(&h[r2.z >> BIN_SHIFT], 1); atomicAdd(&h[r2.w >> BIN_SHIFT], 1); }
    if (v3) { atomicAdd(&h[r3.x >> BIN_SHIFT], 1); atomicAdd(&h[r3.y >> BIN_SHIFT], 1);
              atomicAdd(&h[r3.z >> BIN_SHIFT], 1); atomicAdd(&h[r3.w >> BIN_SHIFT], 1); }
    __syncthreads();
    for (int i = threadIdx.x; i < NBINS; i += 256) {
        int v = h[i];
        histG[blockIdx.x * NBINS + i] = v;
        if (v) atomicAdd(&binTot[i], v);
    }
}

// histG[chunk][bin] -> global start offsets: one 64-lane wave per bin.
// Bin prefix (exclusive scan of binTot) computed in-block by direct reduction
// over the L2-resident binTot array; then shfl-based scan over the 293 chunks.
__global__ __launch_bounds__(64) void rewrite_kernel(int* __restrict__ histG,
                                                     const int* __restrict__ binTot,
                                                     int* __restrict__ binStart) {
    int b    = blockIdx.x;
    int lane = threadIdx.x;
    int pre = 0;
    for (int i = lane; i < b; i += 64) pre += binTot[i];
#pragma unroll
    for (int off = 1; off < 64; off <<= 1) pre += __shfl_xor(pre, off, 64);
    if (lane == 0) binStart[b] = pre;
    if (b == 0 && lane == 0) binStart[NBINS] = N_EDGES;
    int carry = pre;
    for (int base = 0; base < NCHUNKS; base += 64) {
        int idx = base + lane;
        int v = (idx < NCHUNKS) ? histG[idx * NBINS + b] : 0;
        int incl = v;
        for (int off = 1; off < 64; off <<= 1) {
            int t = __shfl_up(incl, off, 64);
            if (lane >= off) incl += t;
        }
        if (idx < NCHUNKS) histG[idx * NBINS + b] = carry + incl - v;
        carry += __shfl(incl, 63, 64);
    }
}

// Phase A2: place packed (col<<8 | row&255) into bin-major tmp.
__global__ __launch_bounds__(256) void placeA_kernel(const int* __restrict__ row,
                                                     const int* __restrict__ col,
                                                     const int* __restrict__ histG,
                                                     int* __restrict__ tmp) {
    __shared__ int ofs[NBINS];
    for (int i = threadIdx.x; i < NBINS; i += 256)
        ofs[i] = histG[blockIdx.x * NBINS + i];
    __syncthreads();
    const int4* row4 = (const int4*)row;
    const int4* col4 = (const int4*)col;
    int base4 = blockIdx.x * (CHUNK / 4);
    int end4  = min(base4 + CHUNK / 4, N_EDGES / 4);
    int i0 = base4 + threadIdx.x;
    int i1 = i0 + 256, i2 = i0 + 512, i3 = i0 + 768;
    int4 r0, r1, r2, r3, c0, c1, c2, c3;
    bool v0 = i0 < end4, v1 = i1 < end4, v2 = i2 < end4, v3 = i3 < end4;
    if (v0) { r0 = row4[i0]; c0 = col4[i0]; }
    if (v1) { r1 = row4[i1]; c1 = col4[i1]; }
    if (v2) { r2 = row4[i2]; c2 = col4[i2]; }
    if (v3) { r3 = row4[i3]; c3 = col4[i3]; }
    auto put = [&](int r, int c) {
        int pos = atomicAdd(&ofs[r >> BIN_SHIFT], 1);
        tmp[pos] = (c << BIN_SHIFT) | (r & 255);
    };
    if (v0) { put(r0.x, c0.x); put(r0.y, c0.y); put(r0.z, c0.z); put(r0.w, c0.w); }
    if (v1) { put(r1.x, c1.x); put(r1.y, c1.y); put(r1.z, c1.z); put(r1.w, c1.w); }
    if (v2) { put(r2.x, c2.x); put(r2.y, c2.y); put(r2.z, c2.z); put(r2.w, c2.w); }
    if (v3) { put(r3.x, c3.x); put(r3.y, c3.y); put(r3.z, c3.z); put(r3.w, c3.w); }
}

// Phase B: one workgroup per bin; LDS counting sort by (row&255); emits
// HYB records {c0..c5, jb, deg} + col_e (overflow) + dis/invd + FUSED conv
// (g0 = x*dis bf16) for its contiguous 256-node range.
__global__ __launch_bounds__(256) void binsort_kernel(const int* __restrict__ tmp,
                                                      const int* __restrict__ binStart,
                                                      int* __restrict__ col_e,
                                                      uint4* __restrict__ rec4,
                                                      float* __restrict__ dis,
                                                      float* __restrict__ invd,
                                                      const float* __restrict__ ue,
                                                      const float* __restrict__ ie,
                                                      unsigned short* __restrict__ g0) {
    __shared__ int hist[256];
    __shared__ int lofs[256];
    __shared__ int colsOut[BIN_CAP];
    int b  = blockIdx.x;
    int jb = binStart[b], je = binStart[b + 1];
    int n  = je - jb;
    hist[threadIdx.x] = 0;
    __syncthreads();
    int ed[8], rk[8];
    int cnt = 0;
    for (int i = threadIdx.x; i < n && cnt < 8; i += 256) {
        int rc = tmp[jb + i];
        ed[cnt] = rc;
        rk[cnt] = atomicAdd(&hist[rc & 255], 1);
        cnt++;
    }
    __syncthreads();
    int deg = hist[threadIdx.x];
    lofs[threadIdx.x] = deg;
    __syncthreads();
    for (int off = 1; off < 256; off <<= 1) {
        int t = (threadIdx.x >= off) ? lofs[threadIdx.x - off] : 0;
        __syncthreads();
        lofs[threadIdx.x] += t;
        __syncthreads();
    }
    int myEx = lofs[threadIdx.x] - deg;
    int node = (b << BIN_SHIFT) + threadIdx.x;
    if (node < N_NODES) {
        float fd = (float)deg;
        dis[node]  = (deg > 0) ? rsqrtf(fd) : 0.0f;
        invd[node] = (deg > 0) ? sqrtf(fd)  : 0.0f;
    }
    lofs[threadIdx.x] = myEx;
    __syncthreads();
    for (int k = 0; k < cnt; ++k)
        colsOut[lofs[ed[k] & 255] + rk[k]] = ((unsigned)ed[k]) >> BIN_SHIFT;
    __syncthreads();
    for (int i = threadIdx.x; i < n; i += 256)
        col_e[jb + i] = colsOut[i];
    if (node < N_NODES) {
        uint4 ra, rb;
        ra.x = (deg > 0) ? (unsigned)colsOut[myEx + 0] : 0u;
        ra.y = (deg > 1) ? (unsigned)colsOut[myEx + 1] : 0u;
        ra.z = (deg > 2) ? (unsigned)colsOut[myEx + 2] : 0u;
        ra.w = (deg > 3) ? (unsigned)colsOut[myEx + 3] : 0u;
        rb.x = (deg > 4) ? (unsigned)colsOut[myEx + 4] : 0u;
        rb.y = (deg > 5) ? (unsigned)colsOut[myEx + 5] : 0u;
        rb.z = (unsigned)(jb + myEx);
        rb.w = (unsigned)deg;
        rec4[2 * node]     = ra;
        rec4[2 * node + 1] = rb;
    }

    // ---- fused conv: g0 rows for nodes [b*256, b*256+256), 8 lanes/node ----
    int q = threadIdx.x & 7;
    for (int pass = 0; pass < 8; ++pass) {
        int nl = pass * 32 + (threadIdx.x >> 3);
        int nd = (b << BIN_SHIFT) + nl;
        if (nd >= N_NODES) break;
        int dg = hist[nl];
        float w = (dg > 0) ? rsqrtf((float)dg) : 0.0f;
        const float* src = (nd < N_USERS) ? (ue + nd * DIM)
                                          : (ie + (nd - N_USERS) * DIM);
        float4 x0 = ((const float4*)src)[2 * q];
        float4 x1 = ((const float4*)src)[2 * q + 1];
        uint4 o;
        o.x = packbf(w * x0.x, w * x0.y);
        o.y = packbf(w * x0.z, w * x0.w);
        o.z = packbf(w * x1.x, w * x1.y);
        o.w = packbf(w * x1.z, w * x1.w);
        ((uint4*)(g0 + nd * DIM))[q] = o;
    }
}

// ---------------------------------------------------------------------------
// HYB (ELL-6 + CSR overflow) bf16 pull: 8 lanes/node. One 32 B record load
// gives deg + first 6 cols -> gathers issue after ONE latency instead of the
// CSR row_ptr->col->gather 3-deep chain (s_waitcnt is wave-wide, so each
// stage costs a full latency for the whole wave). Overflow (deg>6, ~11% of
// nodes, ~4.7% of edges) falls back to col_e. Accumulation order matches the
// CSR version exactly.
// g_{l+1}[r] = dis_r^2 * sum g_l[c].
// FINAL: out = 0.25*(x + (g1+g2)*sqrt(deg) + dis*sum g2[c])
template <bool FINAL>
__global__ __launch_bounds__(256) void pull_kernel(
        const unsigned short* __restrict__ g_in,
        const uint4* __restrict__ rec4, const int* __restrict__ col_e,
        const float* __restrict__ dis, const float* __restrict__ invd,
        const float* __restrict__ ue, const float* __restrict__ ie,
        const unsigned short* __restrict__ gA,
        const unsigned short* __restrict__ gB,
        unsigned short* __restrict__ g_out,
        float* __restrict__ out) {
    int gid  = blockIdx.x * blockDim.x + threadIdx.x;
    int node = gid >> 3;
    int q    = gid & 7;
    if (node >= N_NODES) return;
    uint4 ra = rec4[2 * node];        // c0..c3
    uint4 rb = rec4[2 * node + 1];    // c4, c5, jb, deg
    int deg = (int)rb.w;
    int jb  = (int)rb.z;
    const uint4* gin4 = (const uint4*)g_in;   // row = 8 uint4

    float acc[8];
#pragma unroll
    for (int k = 0; k < 8; ++k) acc[k] = 0.f;

    auto accum = [&](uint4 u) {
        acc[0] += blo(u.x); acc[1] += bhi(u.x);
        acc[2] += blo(u.y); acc[3] += bhi(u.y);
        acc[4] += blo(u.z); acc[5] += bhi(u.z);
        acc[6] += blo(u.w); acc[7] += bhi(u.w);
    };

    bool p0 = deg > 0, p1 = deg > 1, p2 = deg > 2,
         p3 = deg > 3, p4 = deg > 4, p5 = deg > 5;
    uint4 u0, u1, u2, u3, u4, u5;
    if (p0) u0 = gin4[ra.x * 8 + q];
    if (p1) u1 = gin4[ra.y * 8 + q];
    if (p2) u2 = gin4[ra.z * 8 + q];
    if (p3) u3 = gin4[ra.w * 8 + q];
    if (p4) u4 = gin4[rb.x * 8 + q];
    if (p5) u5 = gin4[rb.y * 8 + q];
    if (p0) accum(u0);
    if (p1) accum(u1);
    if (p2) accum(u2);
    if (p3) accum(u3);
    if (p4) accum(u4);
    if (p5) accum(u5);

    // overflow path (deg > 6): classic CSR batched-4 loop over col_e
    int j  = jb + 6;
    int je = jb + deg;
    for (; j + 3 < je; j += 4) {
        int c0 = col_e[j], c1 = col_e[j + 1], c2 = col_e[j + 2], c3 = col_e[j + 3];
        uint4 v0 = gin4[c0 * 8 + q];
        uint4 v1 = gin4[c1 * 8 + q];
        uint4 v2 = gin4[c2 * 8 + q];
        uint4 v3 = gin4[c3 * 8 + q];
        accum(v0); accum(v1); accum(v2); accum(v3);
    }
    for (; j < je; ++j) {
        uint4 v = gin4[col_e[j] * 8 + q];
        accum(v);
    }

    float dr = dis[node];
    if (!FINAL) {
        float s = dr * dr;
        uint4 o;
        o.x = packbf(s * acc[0], s * acc[1]);
        o.y = packbf(s * acc[2], s * acc[3]);
        o.z = packbf(s * acc[4], s * acc[5]);
        o.w = packbf(s * acc[6], s * acc[7]);
        ((uint4*)(g_out + node * DIM))[q] = o;
    } else {
        float iv = invd[node];
        const float* xs = (node < N_USERS) ? (ue + node * DIM)
                                           : (ie + (node - N_USERS) * DIM);
        float4 x0 = ((const float4*)xs)[2 * q];
        float4 x1 = ((const float4*)xs)[2 * q + 1];
        uint4 a = ((const uint4*)gA)[node * 8 + q];
        uint4 bb = ((const uint4*)gB)[node * 8 + q];
        float4 o0, o1;
        o0.x = 0.25f * (x0.x + (blo(a.x) + blo(bb.x)) * iv + dr * acc[0]);
        o0.y = 0.25f * (x0.y + (bhi(a.x) + bhi(bb.x)) * iv + dr * acc[1]);
        o0.z = 0.25f * (x0.z + (blo(a.y) + blo(bb.y)) * iv + dr * acc[2]);
        o0.w = 0.25f * (x0.w + (bhi(a.y) + bhi(bb.y)) * iv + dr * acc[3]);
        o1.x = 0.25f * (x1.x + (blo(a.z) + blo(bb.z)) * iv + dr * acc[4]);
        o1.y = 0.25f * (x1.y + (bhi(a.z) + bhi(bb.z)) * iv + dr * acc[5]);
        o1.z = 0.25f * (x1.z + (blo(a.w) + blo(bb.w)) * iv + dr * acc[6]);
        o1.w = 0.25f * (x1.w + (bhi(a.w) + bhi(bb.w)) * iv + dr * acc[7]);
        ((float4*)out)[node * 16 + 2 * q]     = o0;
        ((float4*)out)[node * 16 + 2 * q + 1] = o1;
    }
}

extern "C" void kernel_launch(void* const* d_in, const int* in_sizes, int n_in,
                              void* d_out, int out_size, void* d_ws, size_t ws_size,
                              hipStream_t stream) {
    const float* ue  = (const float*)d_in[0];
    const float* ie  = (const float*)d_in[1];
    const int*   ei  = (const int*)d_in[2];
    const int*   row = ei;
    const int*   col = ei + N_EDGES;
    float*       out = (float*)d_out;

    // workspace layout (~138 MB)
    size_t gElems = (size_t)N_NODES * DIM;                 // 19.2 M
    unsigned short* g0 = (unsigned short*)d_ws;            // 38.4 MB
    unsigned short* g1 = g0 + gElems;                      // 38.4 MB
    unsigned short* g2 = g1 + gElems;                      // 38.4 MB
    int*   tmp      = (int*)(g2 + gElems);                 // 4.8 MB (packed)
    int*   col_e    = tmp + N_EDGES;                       // 4.8 MB
    uint4* rec4     = (uint4*)(col_e + N_EDGES);           // 9.6 MB (HYB recs)
    float* dis      = (float*)(rec4 + 2 * N_NODES);
    float* invd     = dis + N_NODES;
    int*   histG    = (int*)(invd + N_NODES);              // 293*1172*4 = 1.37 MB
    int*   binTot   = histG + NCHUNKS * NBINS;
    int*   binStart = binTot + NBINS;

    const int B  = 256;
    const int GP = (N_NODES * 8 + B - 1) / B;

    // ---- CSR build: LDS counting sort, no global fine-grained scatter ----
    hipMemsetAsync(binTot, 0, (size_t)NBINS * sizeof(int), stream);
    histA_kernel   <<<NCHUNKS, B, 0, stream>>>(row, histG, binTot);
    rewrite_kernel <<<NBINS, 64, 0, stream>>>(histG, binTot, binStart);
    placeA_kernel  <<<NCHUNKS, B, 0, stream>>>(row, col, histG, tmp);
    binsort_kernel <<<NBINS, B, 0, stream>>>(tmp, binStart, col_e, rec4, dis, invd,
                                             ue, ie, g0);

    // ---- 3 bf16 HYB pull layers; acc + scale fused into the last epilogue ----
    pull_kernel<false><<<GP, B, 0, stream>>>(g0, rec4, col_e, dis, invd,
                                             nullptr, nullptr, nullptr, nullptr, g1, nullptr);
    pull_kernel<false><<<GP, B, 0, stream>>>(g1, rec4, col_e, dis, invd,
                                             nullptr, nullptr, nullptr, nullptr, g2, nullptr);
    pull_kernel<true ><<<GP, B, 0, stream>>>(g2, rec4, col_e, dis, invd,
                                             ue, ie, g1, g2, nullptr, out);
}

// Round 4
// 304.443 us; speedup vs baseline: 4.8559x; 1.0180x over previous
//
#include <hip/hip_runtime.h>

#define N_USERS   200000
#define N_ITEMS   100000
#define DIM       64
#define N_NODES   300000
#define N_EDGES   1200000
#define BIN_SHIFT 8
#define NBINS     1172            // ceil(300000/256)
#define CHUNK     4096
#define NCHUNKS   293             // ceil(1200000/4096)
#define BIN_CAP   2048            // mean edges/bin = 1024 -> huge margin

// ---- bf16 helpers (manual RNE; no NaN inputs here) ------------------------
__device__ __forceinline__ unsigned short f2b(float f) {
    unsigned u = __float_as_uint(f);
    u += 0x7FFFu + ((u >> 16) & 1u);
    return (unsigned short)(u >> 16);
}
__device__ __forceinline__ float blo(unsigned w) { return __uint_as_float(w << 16); }
__device__ __forceinline__ float bhi(unsigned w) { return __uint_as_float(w & 0xFFFF0000u); }
__device__ __forceinline__ unsigned packbf(float lo, float hi) {
    return (unsigned)f2b(lo) | ((unsigned)f2b(hi) << 16);
}

// ---------------------------------------------------------------------------
// Phase A1: per-chunk histogram over bins. int4 loads, 4 outstanding before use.
__global__ __launch_bounds__(256) void histA_kernel(const int* __restrict__ row,
                                                    int* __restrict__ histG,
                                                    int* __restrict__ binTot) {
    __shared__ int h[NBINS];
    for (int i = threadIdx.x; i < NBINS; i += 256) h[i] = 0;
    __syncthreads();
    const int4* row4 = (const int4*)row;
    int base4 = blockIdx.x * (CHUNK / 4);                 // N_EDGES % 4 == 0
    int end4  = min(base4 + CHUNK / 4, N_EDGES / 4);
    int i0 = base4 + threadIdx.x;
    int i1 = i0 + 256, i2 = i0 + 512, i3 = i0 + 768;
    int4 r0, r1, r2, r3;
    bool v0 = i0 < end4, v1 = i1 < end4, v2 = i2 < end4, v3 = i3 < end4;
    if (v0) r0 = row4[i0];
    if (v1) r1 = row4[i1];
    if (v2) r2 = row4[i2];
    if (v3) r3 = row4[i3];
    if (v0) { atomicAdd(&h[r0.x >> BIN_SHIFT], 1); atomicAdd(&h[r0.y >> BIN_SHIFT], 1);
              atomicAdd(&h[r0.z >> BIN_SHIFT], 1); atomicAdd(&h[r0.w >> BIN_SHIFT], 1); }
    if (v1) { atomicAdd(&h[r1.x >> BIN_SHIFT], 1); atomicAdd(&h[r1.y >> BIN_SHIFT], 1);
              atomicAdd(&h[r1.z >> BIN_SHIFT], 1); atomicAdd(&h[r1.w >> BIN_SHIFT], 1); }
    if (v2) { atomicAdd(&h[r2.x >> BIN_SHIFT], 1); atomicAdd(&h[r2.y >> BIN_SHIFT], 1);
              atomicAdd(&h[r2.z >> BIN_SHIFT], 1); atomicAdd(&h[r2.w >> BIN_SHIFT], 1); }
    if (v3) { atomicAdd(&h[r3.x >> BIN_SHIFT], 1); atomicAdd(&h[r3.y >> BIN_SHIFT], 1);
              atomicAdd(&h[r3.z >> BIN_SHIFT], 1); atomicAdd(&h[r3.w >> BIN_SHIFT], 1); }
    __syncthreads();
    for (int i = threadIdx.x; i < NBINS; i += 256) {
        int v = h[i];
        histG[blockIdx.x * NBINS + i] = v;
        if (v) atomicAdd(&binTot[i], v);
    }
}

// histG[chunk][bin] -> global start offsets: one 64-lane wave per bin.
// Bin prefix (exclusive scan of binTot) computed in-block by direct reduction
// over the L2-resident binTot array; then shfl-based scan over the 293 chunks.
__global__ __launch_bounds__(64) void rewrite_kernel(int* __restrict__ histG,
                                                     const int* __restrict__ binTot,
                                                     int* __restrict__ binStart) {
    int b    = blockIdx.x;
    int lane = threadIdx.x;
    int pre = 0;
    for (int i = lane; i < b; i += 64) pre += binTot[i];
#pragma unroll
    for (int off = 1; off < 64; off <<= 1) pre += __shfl_xor(pre, off, 64);
    if (lane == 0) binStart[b] = pre;
    if (b == 0 && lane == 0) binStart[NBINS] = N_EDGES;
    int carry = pre;
    for (int base = 0; base < NCHUNKS; base += 64) {
        int idx = base + lane;
        int v = (idx < NCHUNKS) ? histG[idx * NBINS + b] : 0;
        int incl = v;
        for (int off = 1; off < 64; off <<= 1) {
            int t = __shfl_up(incl, off, 64);
            if (lane >= off) incl += t;
        }
        if (idx < NCHUNKS) histG[idx * NBINS + b] = carry + incl - v;
        carry += __shfl(incl, 63, 64);
    }
}

// Phase A2: place packed (col<<8 | row&255) into bin-major tmp.
__global__ __launch_bounds__(256) void placeA_kernel(const int* __restrict__ row,
                                                     const int* __restrict__ col,
                                                     const int* __restrict__ histG,
                                                     int* __restrict__ tmp) {
    __shared__ int ofs[NBINS];
    for (int i = threadIdx.x; i < NBINS; i += 256)
        ofs[i] = histG[blockIdx.x * NBINS + i];
    __syncthreads();
    const int4* row4 = (const int4*)row;
    const int4* col4 = (const int4*)col;
    int base4 = blockIdx.x * (CHUNK / 4);
    int end4  = min(base4 + CHUNK / 4, N_EDGES / 4);
    int i0 = base4 + threadIdx.x;
    int i1 = i0 + 256, i2 = i0 + 512, i3 = i0 + 768;
    int4 r0, r1, r2, r3, c0, c1, c2, c3;
    bool v0 = i0 < end4, v1 = i1 < end4, v2 = i2 < end4, v3 = i3 < end4;
    if (v0) { r0 = row4[i0]; c0 = col4[i0]; }
    if (v1) { r1 = row4[i1]; c1 = col4[i1]; }
    if (v2) { r2 = row4[i2]; c2 = col4[i2]; }
    if (v3) { r3 = row4[i3]; c3 = col4[i3]; }
    auto put = [&](int r, int c) {
        int pos = atomicAdd(&ofs[r >> BIN_SHIFT], 1);
        tmp[pos] = (c << BIN_SHIFT) | (r & 255);
    };
    if (v0) { put(r0.x, c0.x); put(r0.y, c0.y); put(r0.z, c0.z); put(r0.w, c0.w); }
    if (v1) { put(r1.x, c1.x); put(r1.y, c1.y); put(r1.z, c1.z); put(r1.w, c1.w); }
    if (v2) { put(r2.x, c2.x); put(r2.y, c2.y); put(r2.z, c2.z); put(r2.w, c2.w); }
    if (v3) { put(r3.x, c3.x); put(r3.y, c3.y); put(r3.z, c3.z); put(r3.w, c3.w); }
}

// Phase B: one workgroup per bin; LDS counting sort by (row&255); emits
// col_e coalesced + row_ptr + dis/invd + FUSED conv (g0 = x*dis bf16) for
// its contiguous 256-node range.
__global__ __launch_bounds__(256) void binsort_kernel(const int* __restrict__ tmp,
                                                      const int* __restrict__ binStart,
                                                      int* __restrict__ col_e,
                                                      int* __restrict__ row_ptr,
                                                      float* __restrict__ dis,
                                                      float* __restrict__ invd,
                                                      const float* __restrict__ ue,
                                                      const float* __restrict__ ie,
                                                      unsigned short* __restrict__ g0) {
    __shared__ int hist[256];
    __shared__ int lofs[256];
    __shared__ int colsOut[BIN_CAP];
    int b  = blockIdx.x;
    int jb = binStart[b], je = binStart[b + 1];
    int n  = je - jb;
    hist[threadIdx.x] = 0;
    __syncthreads();
    int ed[8], rk[8];
    int cnt = 0;
    for (int i = threadIdx.x; i < n && cnt < 8; i += 256) {
        int rc = tmp[jb + i];
        ed[cnt] = rc;
        rk[cnt] = atomicAdd(&hist[rc & 255], 1);
        cnt++;
    }
    __syncthreads();
    int deg = hist[threadIdx.x];
    lofs[threadIdx.x] = deg;
    __syncthreads();
    for (int off = 1; off < 256; off <<= 1) {
        int t = (threadIdx.x >= off) ? lofs[threadIdx.x - off] : 0;
        __syncthreads();
        lofs[threadIdx.x] += t;
        __syncthreads();
    }
    int myEx = lofs[threadIdx.x] - deg;
    int node = (b << BIN_SHIFT) + threadIdx.x;
    if (node < N_NODES) {
        row_ptr[node] = jb + myEx;
        float fd = (float)deg;
        dis[node]  = (deg > 0) ? rsqrtf(fd) : 0.0f;
        invd[node] = (deg > 0) ? sqrtf(fd)  : 0.0f;
    }
    if (b == 0 && threadIdx.x == 0) row_ptr[N_NODES] = N_EDGES;
    lofs[threadIdx.x] = myEx;
    __syncthreads();
    for (int k = 0; k < cnt; ++k)
        colsOut[lofs[ed[k] & 255] + rk[k]] = ((unsigned)ed[k]) >> BIN_SHIFT;
    __syncthreads();
    for (int i = threadIdx.x; i < n; i += 256)
        col_e[jb + i] = colsOut[i];

    // ---- fused conv: g0 rows for nodes [b*256, b*256+256), 8 lanes/node ----
    int q = threadIdx.x & 7;
    for (int pass = 0; pass < 8; ++pass) {
        int nl = pass * 32 + (threadIdx.x >> 3);
        int nd = (b << BIN_SHIFT) + nl;
        if (nd >= N_NODES) break;
        int dg = hist[nl];
        float w = (dg > 0) ? rsqrtf((float)dg) : 0.0f;
        const float* src = (nd < N_USERS) ? (ue + nd * DIM)
                                          : (ie + (nd - N_USERS) * DIM);
        float4 x0 = ((const float4*)src)[2 * q];
        float4 x1 = ((const float4*)src)[2 * q + 1];
        uint4 o;
        o.x = packbf(w * x0.x, w * x0.y);
        o.y = packbf(w * x0.z, w * x0.w);
        o.z = packbf(w * x1.x, w * x1.y);
        o.w = packbf(w * x1.z, w * x1.w);
        ((uint4*)(g0 + nd * DIM))[q] = o;
    }
}

// ---------------------------------------------------------------------------
// Atomic-free bf16 pull: 8 lanes/node, 16 B gathers, 4-way edge unroll,
// PREDICATED 3-wide tail (one latency instead of up to 3 serial ones --
// 44% of nodes have deg<=3 at Poisson lambda=4).
// g_{l+1}[r] = dis_r^2 * sum g_l[c].
// FINAL: out = 0.25*(x + (g1+g2)*sqrt(deg) + dis*sum g2[c])
template <bool FINAL>
__global__ __launch_bounds__(256) void pull_kernel(
        const unsigned short* __restrict__ g_in,
        const int* __restrict__ row_ptr, const int* __restrict__ col_e,
        const float* __restrict__ dis, const float* __restrict__ invd,
        const float* __restrict__ ue, const float* __restrict__ ie,
        const unsigned short* __restrict__ gA,
        const unsigned short* __restrict__ gB,
        unsigned short* __restrict__ g_out,
        float* __restrict__ out) {
    int gid  = blockIdx.x * blockDim.x + threadIdx.x;
    int node = gid >> 3;
    int q    = gid & 7;
    if (node >= N_NODES) return;
    int jb = row_ptr[node];
    int je = row_ptr[node + 1];
    const uint4* gin4 = (const uint4*)g_in;   // row = 8 uint4

    float acc[8];
#pragma unroll
    for (int k = 0; k < 8; ++k) acc[k] = 0.f;

    auto accum = [&](uint4 u) {
        acc[0] += blo(u.x); acc[1] += bhi(u.x);
        acc[2] += blo(u.y); acc[3] += bhi(u.y);
        acc[4] += blo(u.z); acc[5] += bhi(u.z);
        acc[6] += blo(u.w); acc[7] += bhi(u.w);
    };

    int j = jb;
    for (; j + 3 < je; j += 4) {
        int c0 = col_e[j], c1 = col_e[j + 1], c2 = col_e[j + 2], c3 = col_e[j + 3];
        uint4 u0 = gin4[c0 * 8 + q];
        uint4 u1 = gin4[c1 * 8 + q];
        uint4 u2 = gin4[c2 * 8 + q];
        uint4 u3 = gin4[c3 * 8 + q];
        accum(u0); accum(u1); accum(u2); accum(u3);
    }
    int rem = je - j;                          // 0..3
    if (rem > 0) {
        bool p1 = rem > 1, p2 = rem > 2;
        int c0 = col_e[j];
        int c1, c2;
        if (p1) c1 = col_e[j + 1];
        if (p2) c2 = col_e[j + 2];
        uint4 u0 = gin4[c0 * 8 + q];
        uint4 u1, u2;
        if (p1) u1 = gin4[c1 * 8 + q];
        if (p2) u2 = gin4[c2 * 8 + q];
        accum(u0);
        if (p1) accum(u1);
        if (p2) accum(u2);
    }

    float dr = dis[node];
    if (!FINAL) {
        float s = dr * dr;
        uint4 o;
        o.x = packbf(s * acc[0], s * acc[1]);
        o.y = packbf(s * acc[2], s * acc[3]);
        o.z = packbf(s * acc[4], s * acc[5]);
        o.w = packbf(s * acc[6], s * acc[7]);
        ((uint4*)(g_out + node * DIM))[q] = o;
    } else {
        float iv = invd[node];
        const float* xs = (node < N_USERS) ? (ue + node * DIM)
                                           : (ie + (node - N_USERS) * DIM);
        float4 x0 = ((const float4*)xs)[2 * q];
        float4 x1 = ((const float4*)xs)[2 * q + 1];
        uint4 a = ((const uint4*)gA)[node * 8 + q];
        uint4 b = ((const uint4*)gB)[node * 8 + q];
        float4 o0, o1;
        o0.x = 0.25f * (x0.x + (blo(a.x) + blo(b.x)) * iv + dr * acc[0]);
        o0.y = 0.25f * (x0.y + (bhi(a.x) + bhi(b.x)) * iv + dr * acc[1]);
        o0.z = 0.25f * (x0.z + (blo(a.y) + blo(b.y)) * iv + dr * acc[2]);
        o0.w = 0.25f * (x0.w + (bhi(a.y) + bhi(b.y)) * iv + dr * acc[3]);
        o1.x = 0.25f * (x1.x + (blo(a.z) + blo(b.z)) * iv + dr * acc[4]);
        o1.y = 0.25f * (x1.y + (bhi(a.z) + bhi(b.z)) * iv + dr * acc[5]);
        o1.z = 0.25f * (x1.z + (blo(a.w) + blo(b.w)) * iv + dr * acc[6]);
        o1.w = 0.25f * (x1.w + (bhi(a.w) + bhi(b.w)) * iv + dr * acc[7]);
        ((float4*)out)[node * 16 + 2 * q]     = o0;
        ((float4*)out)[node * 16 + 2 * q + 1] = o1;
    }
}

extern "C" void kernel_launch(void* const* d_in, const int* in_sizes, int n_in,
                              void* d_out, int out_size, void* d_ws, size_t ws_size,
                              hipStream_t stream) {
    const float* ue  = (const float*)d_in[0];
    const float* ie  = (const float*)d_in[1];
    const int*   ei  = (const int*)d_in[2];
    const int*   row = ei;
    const int*   col = ei + N_EDGES;
    float*       out = (float*)d_out;

    // workspace layout (~135 MB)
    size_t gElems = (size_t)N_NODES * DIM;                 // 19.2 M
    unsigned short* g0 = (unsigned short*)d_ws;            // 38.4 MB
    unsigned short* g1 = g0 + gElems;                      // 38.4 MB
    unsigned short* g2 = g1 + gElems;                      // 38.4 MB
    int*   tmp      = (int*)(g2 + gElems);                 // 4.8 MB (packed)
    int*   col_e    = tmp + N_EDGES;                       // 4.8 MB
    int*   row_ptr  = col_e + N_EDGES;                     // 1.2 MB
    float* dis      = (float*)(row_ptr + N_NODES + 1);
    float* invd     = dis + N_NODES;
    int*   histG    = (int*)(invd + N_NODES);              // 293*1172*4 = 1.37 MB
    int*   binTot   = histG + NCHUNKS * NBINS;
    int*   binStart = binTot + NBINS;

    const int B  = 256;
    const int GP = (N_NODES * 8 + B - 1) / B;

    // ---- CSR build: LDS counting sort, no global fine-grained scatter ----
    hipMemsetAsync(binTot, 0, (size_t)NBINS * sizeof(int), stream);
    histA_kernel   <<<NCHUNKS, B, 0, stream>>>(row, histG, binTot);
    rewrite_kernel <<<NBINS, 64, 0, stream>>>(histG, binTot, binStart);
    placeA_kernel  <<<NCHUNKS, B, 0, stream>>>(row, col, histG, tmp);
    binsort_kernel <<<NBINS, B, 0, stream>>>(tmp, binStart, col_e, row_ptr, dis, invd,
                                             ue, ie, g0);

    // ---- 3 bf16 pull layers; acc + scale fused into the last epilogue ----
    pull_kernel<false><<<GP, B, 0, stream>>>(g0, row_ptr, col_e, dis, invd,
                                             nullptr, nullptr, nullptr, nullptr, g1, nullptr);
    pull_kernel<false><<<GP, B, 0, stream>>>(g1, row_ptr, col_e, dis, invd,
                                             nullptr, nullptr, nullptr, nullptr, g2, nullptr);
    pull_kernel<true ><<<GP, B, 0, stream>>>(g2, row_ptr, col_e, dis, invd,
                                             ue, ie, g1, g2, nullptr, out);
}